// Round 5
// baseline (11412.166 us; speedup 1.0000x reference)
//
#include <hip/hip_runtime.h>
#include <hip/hip_fp16.h>

typedef _Float16 f16;
typedef _Float16 f16x2 __attribute__((ext_vector_type(2)));
typedef _Float16 f16x8 __attribute__((ext_vector_type(8)));
typedef float f32x4 __attribute__((ext_vector_type(4)));

#define B_    32
#define T_    2048
#define E_    512
#define H_    256
#define G4_   1024
#define VOCAB_ 50257

// ---------------- workspace layout (bytes) ----------------
static const size_t WS_XG   = 0;            // f16 [65536][1024] = 134217728
static const size_t WS_WIH  = 134217728ull; // f16 [1024][512]   = 1048576
static const size_t WS_WFR  = 135266304ull; // uint4 [2][8][4][8][64] = 524288
static const size_t WS_HX   = 135790592ull; // h exchange [2 pair][2 dbuf][2 half][4096] = 32768
static const size_t WS_FLG  = 135823360ull; // u32 flags (256 B)
static const size_t WS_MB   = 135823616ull; // u32 [32][64] mask bits = 8192
static const size_t WS_BSUM = 135831808ull; // f32 [1024] = 4096
static const size_t WS_POOL = 135835904ull; // f32 [32][256] = 32768

__device__ __forceinline__ unsigned pack2f(float a, float b) {
    f16x2 h; h.x = (f16)a; h.y = (f16)b;
    return __builtin_bit_cast(unsigned, h);
}

__device__ __forceinline__ float sigm(float v) {
    return 1.f / (1.f + exp2f(-1.44269504f * v));
}
__device__ __forceinline__ float tanhr(float v) {
    float t = exp2f(-2.88539008f * fabsf(v));   // e^(-2|v|)
    float r = (1.f - t) / (1.f + t);
    return v < 0.f ? -r : r;
}

__device__ __forceinline__ int detect64(const int* x) {
    return (x[1] == 0 && x[3] == 0 && x[5] == 0) ? 1 : 0;
}

// ---------------- prep: wih f16, bsum, B-fragments of w_hh, mask bits, flag reset ----------------
// B-frag (half,w,n,kt,lane): W[gate = n*256 + half*128 + w*16 + (lane&15)]
//                            [k = kt*32 + (lane>>4)*8 .. +8]  (8 f16 = uint4)
__global__ void prep_k(const int* __restrict__ x,
                       const float* __restrict__ w_ih, const float* __restrict__ w_hh,
                       const float* __restrict__ b_ih, const float* __restrict__ b_hh,
                       f16* __restrict__ wih16, uint4* __restrict__ wfr,
                       unsigned* __restrict__ mb, unsigned* __restrict__ flg,
                       float* __restrict__ bsum)
{
    const int gid = blockIdx.x * blockDim.x + threadIdx.x;
    const int stride = gridDim.x * blockDim.x;
    const int is64 = detect64(x);
    for (int i = gid; i < G4_*E_; i += stride) wih16[i] = (f16)w_ih[i];
    for (int i = gid; i < G4_; i += stride) bsum[i] = b_ih[i] + b_hh[i];
    for (int i = gid; i < 64; i += stride) flg[i] = 0u;
    for (int n = gid; n < 2*8*4*8*64; n += stride) {
        const int lane = n & 63, kt = (n >> 6) & 7, gt = (n >> 9) & 3;
        const int w = (n >> 11) & 7, half = n >> 14;
        const int gate = gt*256 + half*128 + w*16 + (lane & 15);
        const int k0 = kt*32 + (lane >> 4)*8;
        const float* src = w_hh + (size_t)gate*H_ + k0;
        uint4 v;
        v.x = pack2f(src[0], src[1]); v.y = pack2f(src[2], src[3]);
        v.z = pack2f(src[4], src[5]); v.w = pack2f(src[6], src[7]);
        wfr[n] = v;
    }
    for (int i = gid; i < 32*64; i += stride) {
        const int b = i >> 6, wd = i & 63;
        unsigned word = 0;
        for (int tt = 0; tt < 32; ++tt) {
            const size_t ti = ((size_t)b*T_ + wd*32 + tt) << is64;
            word |= (x[ti] != 0 ? 1u : 0u) << tt;
        }
        mb[i] = word;
    }
}

// ---------------- GEMM: xg[t][j*4+gt] = (f16(emb[x]) @ f16(w_ih)^T + bsum) permuted ----------------
__global__ __launch_bounds__(256) void gemm_xg_k(
    const int* __restrict__ x, const float* __restrict__ emb,
    const f16* __restrict__ wih, const float* __restrict__ bsum,
    f16* __restrict__ xg)
{
    __shared__ f16 As[128*32];
    __shared__ f16 Bs[128*32];
    const int tid = threadIdx.x;
    const int bid = blockIdx.x;
    const int mt = bid >> 3, nt = bid & 7;
    const int wv = tid >> 6, lane = tid & 63;
    const int wm = wv & 1, wn = wv >> 1;
    const int ml = lane & 15, kg = lane >> 4;
    const int is64 = detect64(x);
    const int r = tid >> 1, kh = tid & 1;
    int tok = x[(size_t)(mt*128 + r) << is64];
    tok = tok < 0 ? 0 : (tok >= VOCAB_ ? VOCAB_ - 1 : tok);
    const float* arow = emb + (size_t)tok * E_ + kh*16;
    const f16*   brow = wih + (size_t)(nt*128 + r) * E_ + kh*16;

    f32x4 acc[4][4] = {};
    for (int kk = 0; kk < 16; ++kk) {
        const int k0 = kk * 32;
        float4 a0 = *(const float4*)(arow + k0 + 0);
        float4 a1 = *(const float4*)(arow + k0 + 4);
        float4 a2 = *(const float4*)(arow + k0 + 8);
        float4 a3 = *(const float4*)(arow + k0 + 12);
        uint4 bu0 = *(const uint4*)(brow + k0);
        uint4 bu1 = *(const uint4*)(brow + k0 + 8);
        uint4 au0, au1;
        au0.x = pack2f(a0.x, a0.y); au0.y = pack2f(a0.z, a0.w);
        au0.z = pack2f(a1.x, a1.y); au0.w = pack2f(a1.z, a1.w);
        au1.x = pack2f(a2.x, a2.y); au1.y = pack2f(a2.z, a2.w);
        au1.z = pack2f(a3.x, a3.y); au1.w = pack2f(a3.z, a3.w);
        __syncthreads();
        *(uint4*)(&As[r*32 + kh*16 + 0]) = au0;
        *(uint4*)(&As[r*32 + kh*16 + 8]) = au1;
        *(uint4*)(&Bs[r*32 + kh*16 + 0]) = bu0;
        *(uint4*)(&Bs[r*32 + kh*16 + 8]) = bu1;
        __syncthreads();
        f16x8 af[4], bf[4];
        #pragma unroll
        for (int i = 0; i < 4; ++i) {
            af[i] = *(const f16x8*)(&As[(wm*64 + i*16 + ml)*32 + kg*8]);
            bf[i] = *(const f16x8*)(&Bs[(wn*64 + i*16 + ml)*32 + kg*8]);
        }
        #pragma unroll
        for (int i = 0; i < 4; ++i)
            #pragma unroll
            for (int j = 0; j < 4; ++j)
                acc[i][j] = __builtin_amdgcn_mfma_f32_16x16x32_f16(af[i], bf[j], acc[i][j], 0, 0, 0);
    }
    #pragma unroll
    for (int j = 0; j < 4; ++j) {
        const int gc = nt*128 + wn*64 + j*16 + ml;
        const float bs = bsum[gc];
        const int pc = ((gc & 255) << 2) | (gc >> 8);   // gate-interleaved column
        #pragma unroll
        for (int i = 0; i < 4; ++i) {
            #pragma unroll
            for (int q = 0; q < 4; ++q) {
                const int gr = mt*128 + wm*64 + i*16 + kg*4 + q;
                xg[(size_t)gr*G4_ + pc] = (f16)(acc[i][j][q] + bs);
            }
        }
    }
}

// ---------------- recurrence: MFMA, 4 blocks = 2 batch-pairs x 2 gate-halves ----------------
// Block (pair, half): batches [pair*16,+16), hidden j in [half*128,+128).
// 8 waves x 64 lanes. Wave wv owns gates {n*256 + half*128 + wv*16 + (l&15) : n=0..3}.
// D = A(h: 16 batches x 32k) * B(W^T) per 16x16x32 MFMA; lane holds i,f,g,o for
// j = half*128+wv*16+(l&15), batches (l>>4)*4+q -> c/h update fully in-lane.
// Per-step 4KB h-half exchange between pair-blocks via LLC + agent-scope flags.
__global__ __attribute__((amdgpu_flat_work_group_size(512, 512), amdgpu_waves_per_eu(2)))
void recur_k(const f16* __restrict__ xg, const uint4* __restrict__ wfr,
             const unsigned* __restrict__ mb, char* __restrict__ hx,
             unsigned* __restrict__ flg, float* __restrict__ pool)
{
    __shared__ char hlds[16384];   // 2 x [8 kt][64 lanes][16B]  (h as A-fragments)
    const int tid = threadIdx.x, blk = blockIdx.x;
    const int pair = blk >> 1, half = blk & 1;
    const int wv = tid >> 6, lane = tid & 63;
    const int li = lane & 15, lq = lane >> 4;
    const int j = half*128 + wv*16 + li;      // hidden index owned by this thread
    const int bq0 = lq*4;                     // first of 4 batches

    // B-fragments: own-half k-tiles and peer-half k-tiles (static arrays)
    f16x8 wfo[4][4], wfp[4][4];
    {
        const uint4* ws = wfr + (size_t)(half*8 + wv)*4*8*64;
        #pragma unroll
        for (int n = 0; n < 4; ++n) {
            #pragma unroll
            for (int kk = 0; kk < 4; ++kk) {
                wfo[n][kk] = *(const f16x8*)(ws + (n*8 + (half*4 + kk))*64 + lane);
                wfp[n][kk] = *(const f16x8*)(ws + (n*8 + ((half^1)*4 + kk))*64 + lane);
            }
        }
    }
    // zero h(0) buffer
    { uint4 z = {0,0,0,0}; *(uint4*)(hlds + tid*16) = z; }

    // h-write address: h[j][b] -> hlds[kt=j>>5][lane'=b+16*((j>>3)&3)][i=j&7]
    const int hw_base = ((j >> 5)*1024) + ((bq0 + 16*((j >> 3) & 3))*16) + ((j & 7)*2);
    const char* xgb = (const char*)xg;
    unsigned* flags = flg;
    float c[4] = {0.f,0.f,0.f,0.f}, pooled[4] = {0.f,0.f,0.f,0.f};
    unsigned mw[4] = {0,0,0,0};
    unsigned long long budget = 30000000ull;
    __syncthreads();

    for (int t = 0; t < T_; ++t) {
        const int cur = t & 1, nxt = cur ^ 1;
        // ---- poll peer flag, then issue peer-h load (latency hidden under own MFMAs)
        uint2 peer = {0,0};
        if (t > 0) {
            if (tid == 0) {
                while (__hip_atomic_load(&flags[pair*2 + (half^1)], __ATOMIC_ACQUIRE,
                                         __HIP_MEMORY_SCOPE_AGENT) < (unsigned)t) {
                    if (--budget == 0) break;
                    __builtin_amdgcn_s_sleep(1);
                }
            }
            __syncthreads();
            peer = *(const uint2*)(hx + (((size_t)pair*2 + ((t-1)&1))*2 + (half^1))*4096 + tid*8);
        }
        // ---- mask refresh + xg prefetch
        if ((t & 31) == 0) {
            #pragma unroll
            for (int q = 0; q < 4; ++q) mw[q] = mb[(pair*16 + bq0 + q)*64 + (t >> 5)];
        }
        uint2 xv[4];
        #pragma unroll
        for (int q = 0; q < 4; ++q)
            xv[q] = *(const uint2*)(xgb + ((size_t)(pair*16 + bq0 + q)*T_ + t)*2048 + j*8);

        // ---- own-half MFMAs
        f32x4 acc[4] = {};
        #pragma unroll
        for (int kk = 0; kk < 4; ++kk) {
            f16x8 a = *(const f16x8*)(hlds + cur*8192 + (half*4 + kk)*1024 + lane*16);
            #pragma unroll
            for (int n = 0; n < 4; ++n)
                acc[n] = __builtin_amdgcn_mfma_f32_16x16x32_f16(a, wfo[n][kk], acc[n], 0, 0, 0);
        }
        // ---- stage peer half, then peer-half MFMAs
        if (t > 0) {
            *(uint2*)(hlds + cur*8192 + (half^1)*4096 + tid*8) = peer;
            __syncthreads();
        }
        #pragma unroll
        for (int kk = 0; kk < 4; ++kk) {
            f16x8 a = *(const f16x8*)(hlds + cur*8192 + ((half^1)*4 + kk)*1024 + lane*16);
            #pragma unroll
            for (int n = 0; n < 4; ++n)
                acc[n] = __builtin_amdgcn_mfma_f32_16x16x32_f16(a, wfp[n][kk], acc[n], 0, 0, 0);
        }
        // ---- gates -> c/h update (in-lane), pooled
        f16 hnew[4];
        #pragma unroll
        for (int q = 0; q < 4; ++q) {
            f16x2 x01 = __builtin_bit_cast(f16x2, xv[q].x);
            f16x2 x23 = __builtin_bit_cast(f16x2, xv[q].y);
            float gi = sigm (acc[0][q] + (float)x01.x);
            float gf = sigm (acc[1][q] + (float)x01.y);
            float gg = tanhr(acc[2][q] + (float)x23.x);
            float go = sigm (acc[3][q] + (float)x23.y);
            c[q] = gf*c[q] + gi*gg;
            float hv = go * tanhr(c[q]);
            if ((mw[q] >> (t & 31)) & 1) pooled[q] += hv;
            hnew[q] = (f16)hv;
        }
        // ---- write own h(t+1) fragments
        #pragma unroll
        for (int q = 0; q < 4; ++q)
            *(f16*)(hlds + nxt*8192 + hw_base + q*16) = hnew[q];
        __syncthreads();
        // ---- publish own half to peer
        if (t < T_-1) {
            uint2 own = *(const uint2*)(hlds + nxt*8192 + half*4096 + tid*8);
            *(uint2*)(hx + (((size_t)pair*2 + (t&1))*2 + half)*4096 + tid*8) = own;
            __threadfence();
            __syncthreads();
            if (tid == 0)
                __hip_atomic_store(&flags[pair*2 + half], (unsigned)(t+1),
                                   __ATOMIC_RELEASE, __HIP_MEMORY_SCOPE_AGENT);
        }
    }
    #pragma unroll
    for (int q = 0; q < 4; ++q)
        pool[(pair*16 + bq0 + q)*H_ + j] = pooled[q];
}

// ---------------- head: len scan + pooled mean -> relu(lin1) -> lin2 ----------------
__global__ __launch_bounds__(256) void head_k(
    const int* __restrict__ x,
    const float* __restrict__ pool,
    const float* __restrict__ w1, const float* __restrict__ b1,
    const float* __restrict__ w2, const float* __restrict__ b2,
    float* __restrict__ out)
{
    __shared__ float pl[256];
    __shared__ float l1[512];
    __shared__ int wcnt[4];
    const int b = blockIdx.x, tid = threadIdx.x;
    const int is64 = detect64(x);
    const int* xrow = x + (((size_t)b * T_) << is64);
    int cnt = 0;
    for (int k = tid; k < T_; k += 256) cnt += (xrow[(size_t)k << is64] != 0);
    #pragma unroll
    for (int s = 32; s > 0; s >>= 1) cnt += __shfl_xor(cnt, s);
    if ((tid & 63) == 0) wcnt[tid >> 6] = cnt;
    __syncthreads();
    const float inv = 1.f / (float)(wcnt[0] + wcnt[1] + wcnt[2] + wcnt[3]);
    pl[tid] = pool[b*256 + tid] * inv;
    __syncthreads();
    for (int o = tid; o < 512; o += 256) {
        const float4* wrow = (const float4*)(w1 + (size_t)o*256);
        float s = b1[o];
        #pragma unroll 8
        for (int k = 0; k < 64; ++k) {
            float4 wv = wrow[k];
            s += pl[k*4+0]*wv.x + pl[k*4+1]*wv.y + pl[k*4+2]*wv.z + pl[k*4+3]*wv.w;
        }
        l1[o] = fmaxf(s, 0.f);
    }
    __syncthreads();
    if (tid < 20) {
        const float4* wrow = (const float4*)(w2 + (size_t)tid*512);
        float s = b2[tid];
        #pragma unroll 8
        for (int k = 0; k < 128; ++k) {
            float4 wv = wrow[k];
            s += l1[k*4+0]*wv.x + l1[k*4+1]*wv.y + l1[k*4+2]*wv.z + l1[k*4+3]*wv.w;
        }
        out[b*20 + tid] = s;
    }
}

extern "C" void kernel_launch(void* const* d_in, const int* in_sizes, int n_in,
                              void* d_out, int out_size, void* d_ws, size_t ws_size,
                              hipStream_t stream) {
    (void)in_sizes; (void)n_in; (void)out_size; (void)ws_size;
    const int*   x    = (const int*)d_in[0];
    const float* emb  = (const float*)d_in[1];
    const float* w_ih = (const float*)d_in[2];
    const float* w_hh = (const float*)d_in[3];
    const float* b_ih = (const float*)d_in[4];
    const float* b_hh = (const float*)d_in[5];
    const float* w1   = (const float*)d_in[6];
    const float* b1   = (const float*)d_in[7];
    const float* w2   = (const float*)d_in[8];
    const float* b2   = (const float*)d_in[9];
    float* out = (float*)d_out;
    char* ws = (char*)d_ws;

    f16*      xg    = (f16*)(ws + WS_XG);
    f16*      wih16 = (f16*)(ws + WS_WIH);
    uint4*    wfr   = (uint4*)(ws + WS_WFR);
    char*     hx    = ws + WS_HX;
    unsigned* flg   = (unsigned*)(ws + WS_FLG);
    unsigned* mb    = (unsigned*)(ws + WS_MB);
    float*    bsum  = (float*)(ws + WS_BSUM);
    float*    pool  = (float*)(ws + WS_POOL);

    hipLaunchKernelGGL(prep_k, dim3(512), dim3(256), 0, stream,
                       x, w_ih, w_hh, b_ih, b_hh, wih16, wfr, mb, flg, bsum);
    hipLaunchKernelGGL(gemm_xg_k, dim3(4096), dim3(256), 0, stream,
                       x, emb, wih16, bsum, xg);
    hipLaunchKernelGGL(recur_k, dim3(4), dim3(512), 0, stream,
                       xg, wfr, mb, hx, flg, pool);
    hipLaunchKernelGGL(head_k, dim3(32), dim3(256), 0, stream,
                       x, pool, w1, b1, w2, b2, out);
}

// Round 6
// 5248.364 us; speedup vs baseline: 2.1744x; 2.1744x over previous
//
#include <hip/hip_runtime.h>
#include <hip/hip_fp16.h>

typedef _Float16 f16;
typedef _Float16 f16x2 __attribute__((ext_vector_type(2)));
typedef _Float16 f16x8 __attribute__((ext_vector_type(8)));
typedef float f32x4 __attribute__((ext_vector_type(4)));

#define B_    32
#define T_    2048
#define E_    512
#define H_    256
#define G4_   1024
#define VOCAB_ 50257

// ---------------- workspace layout (bytes) ----------------
static const size_t WS_XG   = 0;            // f16 [65536][1024] = 134217728
static const size_t WS_WIH  = 134217728ull; // f16 [1024][512]   = 1048576
static const size_t WS_WREG = 135266304ull; // u32 [192][512]    = 393216
static const size_t WS_WLDS = 135659520ull; // uint4 [8][16][64] = 131072
static const size_t WS_MB   = 135790592ull; // u32 [32][64]      = 8192
static const size_t WS_BSUM = 135798784ull; // f32 [1024]        = 4096
static const size_t WS_POOL = 135802880ull; // f32 [32][256]     = 32768

// recur dynamic LDS: [0,131072) W, [131072,+1024) h dbuf, [132096,+8192) pbuf
#define LDS_BYTES 140288

__device__ __forceinline__ unsigned pack2f(float a, float b) {
    f16x2 h; h.x = (f16)a; h.y = (f16)b;
    return __builtin_bit_cast(unsigned, h);
}

__device__ __forceinline__ float fdot2u(unsigned a, unsigned b, float c) {
#if __has_builtin(__builtin_amdgcn_fdot2)
    return __builtin_amdgcn_fdot2(__builtin_bit_cast(f16x2, a),
                                  __builtin_bit_cast(f16x2, b), c, false);
#else
    f16x2 av = __builtin_bit_cast(f16x2, a), bv = __builtin_bit_cast(f16x2, b);
    return c + (float)av.x * (float)bv.x + (float)av.y * (float)bv.y;
#endif
}

__device__ __forceinline__ float sigm(float v) {
    return 1.f / (1.f + exp2f(-1.44269504f * v));
}
__device__ __forceinline__ float tanhr(float v) {
    float t = exp2f(-2.88539008f * fabsf(v));   // e^(-2|v|)
    float r = (1.f - t) / (1.f + t);
    return v < 0.f ? -r : r;
}

__device__ __forceinline__ int detect64(const int* x) {
    return (x[1] == 0 && x[3] == 0 && x[5] == 0) ? 1 : 0;
}

// ---------------- prep ----------------
// recur mapping: tid -> wv=tid>>6, lane=tid&63; kc=wv&1 (wave-uniform!), jg=wv>>1;
// j = jg*64+lane. Thread owns rows {q*256+j, q=0..3}, k in [kc*128, +128).
// k-slot m in [0,64): k0(m) = kc*128 + (m>>1)*4 + (m&1)*2 (pairs k0,k0+1)
//   (matches readlane order: sA[i] = h dwords 2(kc*32+i), sB[i] = +1)
// REG part m<48: wr[q*48+m]. LDS part m in [48,64): uint4 slot s=q*4+e holds
//   dwords u=0..3 -> m = 48+4e+u.
__global__ void prep_k(const int* __restrict__ x,
                       const float* __restrict__ w_ih, const float* __restrict__ w_hh,
                       const float* __restrict__ b_ih, const float* __restrict__ b_hh,
                       f16* __restrict__ wih16, unsigned* __restrict__ wreg,
                       uint4* __restrict__ wlds, unsigned* __restrict__ mb,
                       float* __restrict__ bsum)
{
    const int gid = blockIdx.x * blockDim.x + threadIdx.x;
    const int stride = gridDim.x * blockDim.x;
    const int is64 = detect64(x);
    for (int i = gid; i < G4_*E_; i += stride) wih16[i] = (f16)w_ih[i];
    for (int i = gid; i < G4_; i += stride) bsum[i] = b_ih[i] + b_hh[i];
    for (int n = gid; n < 192*512; n += stride) {
        const int idx = n >> 9, tid = n & 511;
        const int wv = tid >> 6, lane = tid & 63, kc = wv & 1, jg = wv >> 1;
        const int j = jg*64 + lane;
        const int q = idx / 48, m = idx % 48;
        const int row = q*256 + j;
        const int k0 = kc*128 + (m >> 1)*4 + (m & 1)*2;
        wreg[n] = pack2f(w_hh[row*256 + k0], w_hh[row*256 + k0 + 1]);
    }
    for (int n = gid; n < 8*16*64; n += stride) {
        const int lane = n & 63, s = (n >> 6) & 15, wv = n >> 10;
        const int kc = wv & 1, jg = wv >> 1;
        const int j = jg*64 + lane;
        const int q = s >> 2, e = s & 3;
        const int row = q*256 + j;
        const float* wrow = w_hh + (size_t)row*H_;
        uint4 v; unsigned d[4];
        #pragma unroll
        for (int u = 0; u < 4; ++u) {
            const int m = 48 + 4*e + u;
            const int k0 = kc*128 + (m >> 1)*4 + (m & 1)*2;
            d[u] = pack2f(wrow[k0], wrow[k0 + 1]);
        }
        v.x = d[0]; v.y = d[1]; v.z = d[2]; v.w = d[3];
        wlds[n] = v;
    }
    for (int i = gid; i < 32*64; i += stride) {
        const int b = i >> 6, wd = i & 63;
        unsigned word = 0;
        for (int tt = 0; tt < 32; ++tt) {
            const size_t ti = ((size_t)b*T_ + wd*32 + tt) << is64;
            word |= (x[ti] != 0 ? 1u : 0u) << tt;
        }
        mb[i] = word;
    }
}

// ---------------- GEMM: xg[t][j*4+gt] = (f16(emb[x]) @ f16(w_ih)^T + bsum) permuted ----------------
__global__ __launch_bounds__(256) void gemm_xg_k(
    const int* __restrict__ x, const float* __restrict__ emb,
    const f16* __restrict__ wih, const float* __restrict__ bsum,
    f16* __restrict__ xg)
{
    __shared__ f16 As[128*32];
    __shared__ f16 Bs[128*32];
    const int tid = threadIdx.x;
    const int bid = blockIdx.x;
    const int mt = bid >> 3, nt = bid & 7;
    const int wv = tid >> 6, lane = tid & 63;
    const int wm = wv & 1, wn = wv >> 1;
    const int ml = lane & 15, kg = lane >> 4;
    const int is64 = detect64(x);
    const int r = tid >> 1, kh = tid & 1;
    int tok = x[(size_t)(mt*128 + r) << is64];
    tok = tok < 0 ? 0 : (tok >= VOCAB_ ? VOCAB_ - 1 : tok);
    const float* arow = emb + (size_t)tok * E_ + kh*16;
    const f16*   brow = wih + (size_t)(nt*128 + r) * E_ + kh*16;

    f32x4 acc[4][4] = {};
    for (int kk = 0; kk < 16; ++kk) {
        const int k0 = kk * 32;
        float4 a0 = *(const float4*)(arow + k0 + 0);
        float4 a1 = *(const float4*)(arow + k0 + 4);
        float4 a2 = *(const float4*)(arow + k0 + 8);
        float4 a3 = *(const float4*)(arow + k0 + 12);
        uint4 bu0 = *(const uint4*)(brow + k0);
        uint4 bu1 = *(const uint4*)(brow + k0 + 8);
        uint4 au0, au1;
        au0.x = pack2f(a0.x, a0.y); au0.y = pack2f(a0.z, a0.w);
        au0.z = pack2f(a1.x, a1.y); au0.w = pack2f(a1.z, a1.w);
        au1.x = pack2f(a2.x, a2.y); au1.y = pack2f(a2.z, a2.w);
        au1.z = pack2f(a3.x, a3.y); au1.w = pack2f(a3.z, a3.w);
        __syncthreads();
        *(uint4*)(&As[r*32 + kh*16 + 0]) = au0;
        *(uint4*)(&As[r*32 + kh*16 + 8]) = au1;
        *(uint4*)(&Bs[r*32 + kh*16 + 0]) = bu0;
        *(uint4*)(&Bs[r*32 + kh*16 + 8]) = bu1;
        __syncthreads();
        f16x8 af[4], bf[4];
        #pragma unroll
        for (int i = 0; i < 4; ++i) {
            af[i] = *(const f16x8*)(&As[(wm*64 + i*16 + ml)*32 + kg*8]);
            bf[i] = *(const f16x8*)(&Bs[(wn*64 + i*16 + ml)*32 + kg*8]);
        }
        #pragma unroll
        for (int i = 0; i < 4; ++i)
            #pragma unroll
            for (int j = 0; j < 4; ++j)
                acc[i][j] = __builtin_amdgcn_mfma_f32_16x16x32_f16(af[i], bf[j], acc[i][j], 0, 0, 0);
    }
    #pragma unroll
    for (int j = 0; j < 4; ++j) {
        const int gc = nt*128 + wn*64 + j*16 + ml;
        const float bs = bsum[gc];
        const int pc = ((gc & 255) << 2) | (gc >> 8);   // gate-interleaved column
        #pragma unroll
        for (int i = 0; i < 4; ++i) {
            #pragma unroll
            for (int q = 0; q < 4; ++q) {
                const int gr = mt*128 + wm*64 + i*16 + kg*4 + q;
                xg[(size_t)gr*G4_ + pc] = (f16)(acc[i][j][q] + bs);
            }
        }
    }
}

// ---------------- recurrence: 1 block = 1 batch; h via readlane->SGPR ----------------
// 8 waves: wave wv = (jg = wv>>1, kc = wv&1); j = jg*64+lane.
// Thread owns gates {q*256+j}, k-half [kc*128,+128): 96 k in wr[192], 32 k in LDS.
// h: one ds_read_b64 spreads 128 h-dwords over lanes; readlane -> SGPR broadcast.
// Cross-kc reduce via pbuf LDS; gate tail + c/h update in kc=0 waves.
__global__ __attribute__((amdgpu_flat_work_group_size(512, 512), amdgpu_waves_per_eu(2, 2)))
void recur_k(const f16* __restrict__ xg,
             const unsigned* __restrict__ wreg_g, const uint4* __restrict__ wlds_g,
             const unsigned* __restrict__ mb,
             float* __restrict__ pool)
{
    extern __shared__ char smem[];
    const int tid = threadIdx.x, b = blockIdx.x;
    const int wv = tid >> 6, lane = tid & 63;
    const int kc = wv & 1, jg = wv >> 1;
    const int j = jg*64 + lane;
    const int kcb = kc*32;     // wave-uniform readlane base

    unsigned wr[192];
    #pragma unroll
    for (int i = 0; i < 192; ++i) wr[i] = wreg_g[i*512 + tid];
    #pragma unroll
    for (int i = 0; i < 192; ++i) asm volatile("" : "+v"(wr[i]));   // pin resident
    {
        uint4* wl = (uint4*)smem;
        #pragma unroll
        for (int s = 0; s < 16; ++s)
            wl[wv*1024 + s*64 + lane] = wlds_g[wv*1024 + s*64 + lane];
    }
    if (tid < 256) ((unsigned*)(smem + 131072))[tid] = 0u;   // zero both h buffers

    const char* xgrow = (const char*)xg + (size_t)b * T_ * 2048;
    const char* wbase = smem + wv*16384;
    char* pbuf = smem + 132096;
    float cst = 0.f, pooled = 0.f;
    unsigned mw = 0;
    __syncthreads();

    for (int t = 0; t < T_; ++t) {
        const char* hb = smem + 131072 + (t & 1)*512;
        uint2 hv = *(const uint2*)(hb + lane*8);          // all 128 h-dwords across wave
        uint2 xv = {0, 0};
        if (kc == 0) {
            xv = *(const uint2*)(xgrow + (size_t)t*2048 + j*8);   // prefetch early
            if ((t & 31) == 0) mw = mb[b*64 + (t >> 5)];
        }
        float p[4] = {0.f, 0.f, 0.f, 0.f};

        // ---- phase 0: slots m in [0,32) (h dwords i=0..15)
        {
            unsigned sA[16], sB[16];
            #pragma unroll
            for (int i = 0; i < 16; ++i) {
                sA[i] = __builtin_amdgcn_readlane((int)hv.x, kcb + i);
                sB[i] = __builtin_amdgcn_readlane((int)hv.y, kcb + i);
            }
            #pragma unroll
            for (int m = 0; m < 32; ++m) {
                const unsigned h2 = (m & 1) ? sB[m >> 1] : sA[m >> 1];
                #pragma unroll
                for (int q = 0; q < 4; ++q) p[q] = fdot2u(wr[q*48 + m], h2, p[q]);
            }
        }
        // ---- phase 1: slots m in [32,48) reg + [48,64) LDS (h dwords i=16..31)
        {
            unsigned sA[16], sB[16];
            #pragma unroll
            for (int i = 0; i < 16; ++i) {
                sA[i] = __builtin_amdgcn_readlane((int)hv.x, kcb + 16 + i);
                sB[i] = __builtin_amdgcn_readlane((int)hv.y, kcb + 16 + i);
            }
            #pragma unroll
            for (int m = 32; m < 48; ++m) {
                const unsigned h2 = (m & 1) ? sB[(m >> 1) - 16] : sA[(m >> 1) - 16];
                #pragma unroll
                for (int q = 0; q < 4; ++q) p[q] = fdot2u(wr[q*48 + m], h2, p[q]);
            }
            #pragma unroll
            for (int e = 0; e < 4; ++e) {
                const unsigned hA0 = sA[8 + 2*e], hB0 = sB[8 + 2*e];   // i=24+2e
                const unsigned hA1 = sA[9 + 2*e], hB1 = sB[9 + 2*e];   // i=25+2e
                #pragma unroll
                for (int q = 0; q < 4; ++q) {
                    uint4 w4 = *(const uint4*)(wbase + ((q*4 + e)*64 + lane)*16);
                    p[q] = fdot2u(w4.x, hA0, p[q]);
                    p[q] = fdot2u(w4.y, hB0, p[q]);
                    p[q] = fdot2u(w4.z, hA1, p[q]);
                    p[q] = fdot2u(w4.w, hB1, p[q]);
                }
            }
        }
        // ---- cross-kc reduce through LDS
        *(float4*)(pbuf + wv*1024 + lane*16) = make_float4(p[0], p[1], p[2], p[3]);
        __syncthreads();
        if (kc == 0) {
            float4 pr = *(const float4*)(pbuf + (wv^1)*1024 + lane*16);
            f16x2 x01 = __builtin_bit_cast(f16x2, xv.x);
            f16x2 x23 = __builtin_bit_cast(f16x2, xv.y);
            float gi = sigm (p[0] + pr.x + (float)x01.x);
            float gf = sigm (p[1] + pr.y + (float)x01.y);
            float gg = tanhr(p[2] + pr.z + (float)x23.x);
            float go = sigm (p[3] + pr.w + (float)x23.y);
            cst = gf*cst + gi*gg;
            float hvv = go * tanhr(cst);
            if ((mw >> (t & 31)) & 1) pooled += hvv;
            *(f16*)(smem + 131072 + ((t+1) & 1)*512 + j*2) = (f16)hvv;
        }
        __syncthreads();
    }
    if (kc == 0) pool[b*H_ + j] = pooled;
}

// ---------------- head: len scan + pooled mean -> relu(lin1) -> lin2 ----------------
__global__ __launch_bounds__(256) void head_k(
    const int* __restrict__ x,
    const float* __restrict__ pool,
    const float* __restrict__ w1, const float* __restrict__ b1,
    const float* __restrict__ w2, const float* __restrict__ b2,
    float* __restrict__ out)
{
    __shared__ float pl[256];
    __shared__ float l1[512];
    __shared__ int wcnt[4];
    const int b = blockIdx.x, tid = threadIdx.x;
    const int is64 = detect64(x);
    const int* xrow = x + (((size_t)b * T_) << is64);
    int cnt = 0;
    for (int k = tid; k < T_; k += 256) cnt += (xrow[(size_t)k << is64] != 0);
    #pragma unroll
    for (int s = 32; s > 0; s >>= 1) cnt += __shfl_xor(cnt, s);
    if ((tid & 63) == 0) wcnt[tid >> 6] = cnt;
    __syncthreads();
    const float inv = 1.f / (float)(wcnt[0] + wcnt[1] + wcnt[2] + wcnt[3]);
    pl[tid] = pool[b*256 + tid] * inv;
    __syncthreads();
    for (int o = tid; o < 512; o += 256) {
        const float4* wrow = (const float4*)(w1 + (size_t)o*256);
        float s = b1[o];
        #pragma unroll 8
        for (int k = 0; k < 64; ++k) {
            float4 wv = wrow[k];
            s += pl[k*4+0]*wv.x + pl[k*4+1]*wv.y + pl[k*4+2]*wv.z + pl[k*4+3]*wv.w;
        }
        l1[o] = fmaxf(s, 0.f);
    }
    __syncthreads();
    if (tid < 20) {
        const float4* wrow = (const float4*)(w2 + (size_t)tid*512);
        float s = b2[tid];
        #pragma unroll 8
        for (int k = 0; k < 128; ++k) {
            float4 wv = wrow[k];
            s += l1[k*4+0]*wv.x + l1[k*4+1]*wv.y + l1[k*4+2]*wv.z + l1[k*4+3]*wv.w;
        }
        out[b*20 + tid] = s;
    }
}

extern "C" void kernel_launch(void* const* d_in, const int* in_sizes, int n_in,
                              void* d_out, int out_size, void* d_ws, size_t ws_size,
                              hipStream_t stream) {
    (void)in_sizes; (void)n_in; (void)out_size; (void)ws_size;
    const int*   x    = (const int*)d_in[0];
    const float* emb  = (const float*)d_in[1];
    const float* w_ih = (const float*)d_in[2];
    const float* w_hh = (const float*)d_in[3];
    const float* b_ih = (const float*)d_in[4];
    const float* b_hh = (const float*)d_in[5];
    const float* w1   = (const float*)d_in[6];
    const float* b1   = (const float*)d_in[7];
    const float* w2   = (const float*)d_in[8];
    const float* b2   = (const float*)d_in[9];
    float* out = (float*)d_out;
    char* ws = (char*)d_ws;

    f16*      xg    = (f16*)(ws + WS_XG);
    f16*      wih16 = (f16*)(ws + WS_WIH);
    unsigned* wreg  = (unsigned*)(ws + WS_WREG);
    uint4*    wlds  = (uint4*)(ws + WS_WLDS);
    unsigned* mb    = (unsigned*)(ws + WS_MB);
    float*    bsum  = (float*)(ws + WS_BSUM);
    float*    pool  = (float*)(ws + WS_POOL);

    hipLaunchKernelGGL(prep_k, dim3(512), dim3(256), 0, stream,
                       x, w_ih, w_hh, b_ih, b_hh, wih16, wreg, wlds, mb, bsum);
    hipLaunchKernelGGL(gemm_xg_k, dim3(4096), dim3(256), 0, stream,
                       x, emb, wih16, bsum, xg);
    hipLaunchKernelGGL(recur_k, dim3(32), dim3(512), LDS_BYTES, stream,
                       xg, wreg, wlds, mb, pool);
    hipLaunchKernelGGL(head_k, dim3(32), dim3(256), 0, stream,
                       x, pool, w1, b1, w2, b2, out);
}

// Round 7
// 4455.321 us; speedup vs baseline: 2.5615x; 1.1780x over previous
//
#include <hip/hip_runtime.h>
#include <hip/hip_fp16.h>

typedef _Float16 f16;
typedef _Float16 f16x2 __attribute__((ext_vector_type(2)));
typedef _Float16 f16x8 __attribute__((ext_vector_type(8)));
typedef float f32x4 __attribute__((ext_vector_type(4)));

#define B_    32
#define T_    2048
#define E_    512
#define H_    256
#define G4_   1024
#define VOCAB_ 50257

// ---------------- workspace layout (bytes) ----------------
static const size_t WS_XG   = 0;            // f16 [65536][1024] = 134217728
static const size_t WS_WIH  = 134217728ull; // f16 [1024][512]   = 1048576
static const size_t WS_WREG = 135266304ull; // u32 [192][512]    = 393216
static const size_t WS_WLDS = 135659520ull; // uint4 [8][16][64] = 131072
static const size_t WS_MB   = 135790592ull; // u32 [32][64]      = 8192
static const size_t WS_BSUM = 135798784ull; // f32 [1024]        = 4096
static const size_t WS_POOL = 135802880ull; // f32 [32][256]     = 32768

// recur dynamic LDS: [0,131072) weights, [131072,+1024) h double buffer (2x512B)
#define LDS_BYTES 132096

__device__ __forceinline__ unsigned pack2f(float a, float b) {
    f16x2 h; h.x = (f16)a; h.y = (f16)b;
    return __builtin_bit_cast(unsigned, h);
}

__device__ __forceinline__ float fdot2u(unsigned a, unsigned b, float c) {
#if __has_builtin(__builtin_amdgcn_fdot2)
    return __builtin_amdgcn_fdot2(__builtin_bit_cast(f16x2, a),
                                  __builtin_bit_cast(f16x2, b), c, false);
#else
    f16x2 av = __builtin_bit_cast(f16x2, a), bv = __builtin_bit_cast(f16x2, b);
    return c + (float)av.x * (float)bv.x + (float)av.y * (float)bv.y;
#endif
}

__device__ __forceinline__ float sigm(float v) {
    return 1.f / (1.f + exp2f(-1.44269504f * v));
}
__device__ __forceinline__ float tanhr(float v) {
    float t = exp2f(-2.88539008f * fabsf(v));   // e^(-2|v|)
    float r = (1.f - t) / (1.f + t);
    return v < 0.f ? -r : r;
}

__device__ __forceinline__ int detect64(const int* x) {
    return (x[1] == 0 && x[3] == 0 && x[5] == 0) ? 1 : 0;
}

// ---------------- prep ----------------
// recur mapping: tid in [0,512): j = tid>>1, gp = tid&1.
// Thread owns rows {gp*512 + j, gp*512 + 256 + j} (gp=0: i,f; gp=1: g,o), FULL k.
// Weight dword d in [0,128) of a row covers k = {2d, 2d+1}.
// REG part d<96: wr[row*96 + d]. LDS part d in [96,128): uint4 slot s = row*8+e
// holds dwords d = 96+4e+u (u=0..3); layout [wv][s][lane] x 16B.
__global__ void prep_k(const int* __restrict__ x,
                       const float* __restrict__ w_ih, const float* __restrict__ w_hh,
                       const float* __restrict__ b_ih, const float* __restrict__ b_hh,
                       f16* __restrict__ wih16, unsigned* __restrict__ wreg,
                       uint4* __restrict__ wlds, unsigned* __restrict__ mb,
                       float* __restrict__ bsum)
{
    const int gid = blockIdx.x * blockDim.x + threadIdx.x;
    const int stride = gridDim.x * blockDim.x;
    const int is64 = detect64(x);
    for (int i = gid; i < G4_*E_; i += stride) wih16[i] = (f16)w_ih[i];
    for (int i = gid; i < G4_; i += stride) bsum[i] = b_ih[i] + b_hh[i];
    for (int n = gid; n < 192*512; n += stride) {
        const int idx = n >> 9, tid = n & 511;
        const int j = tid >> 1, gp = tid & 1;
        const int row = idx / 96, d = idx % 96;
        const int R = gp*512 + row*256 + j;
        const int k = 2*d;
        wreg[n] = pack2f(w_hh[(size_t)R*H_ + k], w_hh[(size_t)R*H_ + k + 1]);
    }
    for (int n = gid; n < 8*16*64; n += stride) {
        const int wv = n >> 10, s = (n >> 6) & 15, lane = n & 63;
        const int j = wv*32 + (lane >> 1), gp = lane & 1;
        const int r = s >> 3, e = s & 7;
        const int R = gp*512 + r*256 + j;
        const float* wrow = w_hh + (size_t)R*H_;
        unsigned du[4];
        #pragma unroll
        for (int u = 0; u < 4; ++u) {
            const int k = 2*(96 + 4*e + u);
            du[u] = pack2f(wrow[k], wrow[k + 1]);
        }
        uint4 v; v.x = du[0]; v.y = du[1]; v.z = du[2]; v.w = du[3];
        wlds[n] = v;
    }
    for (int i = gid; i < 32*64; i += stride) {
        const int b = i >> 6, wd = i & 63;
        unsigned word = 0;
        for (int tt = 0; tt < 32; ++tt) {
            const size_t ti = ((size_t)b*T_ + wd*32 + tt) << is64;
            word |= (x[ti] != 0 ? 1u : 0u) << tt;
        }
        mb[i] = word;
    }
}

// ---------------- GEMM: xg[t][j*4+gt] = (f16(emb[x]) @ f16(w_ih)^T + bsum) permuted ----------------
__global__ __launch_bounds__(256) void gemm_xg_k(
    const int* __restrict__ x, const float* __restrict__ emb,
    const f16* __restrict__ wih, const float* __restrict__ bsum,
    f16* __restrict__ xg)
{
    __shared__ f16 As[128*32];
    __shared__ f16 Bs[128*32];
    const int tid = threadIdx.x;
    const int bid = blockIdx.x;
    const int mt = bid >> 3, nt = bid & 7;
    const int wv = tid >> 6, lane = tid & 63;
    const int wm = wv & 1, wn = wv >> 1;
    const int ml = lane & 15, kg = lane >> 4;
    const int is64 = detect64(x);
    const int r = tid >> 1, kh = tid & 1;
    int tok = x[(size_t)(mt*128 + r) << is64];
    tok = tok < 0 ? 0 : (tok >= VOCAB_ ? VOCAB_ - 1 : tok);
    const float* arow = emb + (size_t)tok * E_ + kh*16;
    const f16*   brow = wih + (size_t)(nt*128 + r) * E_ + kh*16;

    f32x4 acc[4][4] = {};
    for (int kk = 0; kk < 16; ++kk) {
        const int k0 = kk * 32;
        float4 a0 = *(const float4*)(arow + k0 + 0);
        float4 a1 = *(const float4*)(arow + k0 + 4);
        float4 a2 = *(const float4*)(arow + k0 + 8);
        float4 a3 = *(const float4*)(arow + k0 + 12);
        uint4 bu0 = *(const uint4*)(brow + k0);
        uint4 bu1 = *(const uint4*)(brow + k0 + 8);
        uint4 au0, au1;
        au0.x = pack2f(a0.x, a0.y); au0.y = pack2f(a0.z, a0.w);
        au0.z = pack2f(a1.x, a1.y); au0.w = pack2f(a1.z, a1.w);
        au1.x = pack2f(a2.x, a2.y); au1.y = pack2f(a2.z, a2.w);
        au1.z = pack2f(a3.x, a3.y); au1.w = pack2f(a3.z, a3.w);
        __syncthreads();
        *(uint4*)(&As[r*32 + kh*16 + 0]) = au0;
        *(uint4*)(&As[r*32 + kh*16 + 8]) = au1;
        *(uint4*)(&Bs[r*32 + kh*16 + 0]) = bu0;
        *(uint4*)(&Bs[r*32 + kh*16 + 8]) = bu1;
        __syncthreads();
        f16x8 af[4], bf[4];
        #pragma unroll
        for (int i = 0; i < 4; ++i) {
            af[i] = *(const f16x8*)(&As[(wm*64 + i*16 + ml)*32 + kg*8]);
            bf[i] = *(const f16x8*)(&Bs[(wn*64 + i*16 + ml)*32 + kg*8]);
        }
        #pragma unroll
        for (int i = 0; i < 4; ++i)
            #pragma unroll
            for (int j = 0; j < 4; ++j)
                acc[i][j] = __builtin_amdgcn_mfma_f32_16x16x32_f16(af[i], bf[j], acc[i][j], 0, 0, 0);
    }
    #pragma unroll
    for (int j = 0; j < 4; ++j) {
        const int gc = nt*128 + wn*64 + j*16 + ml;
        const float bs = bsum[gc];
        const int pc = ((gc & 255) << 2) | (gc >> 8);   // gate-interleaved column
        #pragma unroll
        for (int i = 0; i < 4; ++i) {
            #pragma unroll
            for (int q = 0; q < 4; ++q) {
                const int gr = mt*128 + wm*64 + i*16 + kg*4 + q;
                xg[(size_t)gr*G4_ + pc] = (f16)(acc[i][j][q] + bs);
            }
        }
    }
}

// ---------------- recurrence: 1 block = 1 batch; 2 rows/thread, full k ----------------
// No k-split -> no cross-k reduce, one barrier/step. h via 1 ds_read_b64 +
// readlane SGPR broadcast (valid: all waves need the same h dwords).
// Pair (2j, 2j+1) holds {i,f} / {g,o} of j; one shfl_xor(1) completes the quadruple.
__global__ __attribute__((amdgpu_flat_work_group_size(512, 512), amdgpu_waves_per_eu(2, 2)))
void recur_k(const f16* __restrict__ xg,
             const unsigned* __restrict__ wreg_g, const uint4* __restrict__ wlds_g,
             const unsigned* __restrict__ mb,
             float* __restrict__ pool)
{
    extern __shared__ char smem[];
    const int tid = threadIdx.x, b = blockIdx.x;
    const int wv = tid >> 6, lane = tid & 63;
    const int j = tid >> 1, gp = tid & 1;

    unsigned wr[192];
    #pragma unroll
    for (int i = 0; i < 192; ++i) wr[i] = wreg_g[i*512 + tid];
    #pragma unroll
    for (int i = 0; i < 192; ++i) asm volatile("" : "+v"(wr[i]));   // keep resident
    {
        uint4* wl = (uint4*)smem;
        #pragma unroll
        for (int s = 0; s < 16; ++s)
            wl[wv*1024 + s*64 + lane] = wlds_g[wv*1024 + s*64 + lane];
    }
    if (tid < 256) ((unsigned*)(smem + 131072))[tid] = 0u;   // zero both h buffers

    const char* xgrow = (const char*)xg + (size_t)b * T_ * 2048;
    const char* wbase = smem + wv*16384;
    float cst = 0.f, pooled = 0.f;
    unsigned mw = 0;
    __syncthreads();

    for (int t = 0; t < T_; ++t) {
        const char* hb = smem + 131072 + (t & 1)*512;
        uint2 hv = *(const uint2*)(hb + lane*8);     // wave holds all 128 h dwords
        unsigned xv = *(const unsigned*)(xgrow + (size_t)t*2048 + tid*4);
        if ((t & 31) == 0) mw = mb[b*64 + (t >> 5)];
        float p0 = 0.f, p1 = 0.f;

        // phases 0..2: register weights, h dwords d in [32*ph, 32*ph+32)
        #pragma unroll
        for (int ph = 0; ph < 3; ++ph) {
            unsigned sA[16], sB[16];
            #pragma unroll
            for (int u = 0; u < 16; ++u) {
                sA[u] = __builtin_amdgcn_readlane((int)hv.x, ph*16 + u);
                sB[u] = __builtin_amdgcn_readlane((int)hv.y, ph*16 + u);
            }
            #pragma unroll
            for (int u = 0; u < 16; ++u) {
                const int d0 = ph*32 + 2*u;
                p0 = fdot2u(wr[d0],       sA[u], p0);
                p0 = fdot2u(wr[d0 + 1],   sB[u], p0);
                p1 = fdot2u(wr[96 + d0],     sA[u], p1);
                p1 = fdot2u(wr[96 + d0 + 1], sB[u], p1);
            }
        }
        // phase 3: LDS weights, h dwords d in [96,128)
        {
            unsigned sA[16], sB[16];
            #pragma unroll
            for (int u = 0; u < 16; ++u) {
                sA[u] = __builtin_amdgcn_readlane((int)hv.x, 48 + u);
                sB[u] = __builtin_amdgcn_readlane((int)hv.y, 48 + u);
            }
            #pragma unroll
            for (int e = 0; e < 8; ++e) {
                uint4 w0 = *(const uint4*)(wbase + ((0*8 + e)*64 + lane)*16);
                p0 = fdot2u(w0.x, sA[2*e],   p0);
                p0 = fdot2u(w0.y, sB[2*e],   p0);
                p0 = fdot2u(w0.z, sA[2*e+1], p0);
                p0 = fdot2u(w0.w, sB[2*e+1], p0);
                uint4 w1 = *(const uint4*)(wbase + ((1*8 + e)*64 + lane)*16);
                p1 = fdot2u(w1.x, sA[2*e],   p1);
                p1 = fdot2u(w1.y, sB[2*e],   p1);
                p1 = fdot2u(w1.z, sA[2*e+1], p1);
                p1 = fdot2u(w1.w, sB[2*e+1], p1);
            }
        }
        // pair exchange: (2j) has i,f ; (2j+1) has g,o
        const float q0 = __shfl_xor(p0, 1);
        const float q1 = __shfl_xor(p1, 1);
        const unsigned xq = __shfl_xor((int)xv, 1);
        const f16x2 xvh = __builtin_bit_cast(f16x2, xv);
        const f16x2 xqh = __builtin_bit_cast(f16x2, xq);
        const float pi_ = gp ? q0 : p0, pf_ = gp ? q1 : p1;
        const float pg_ = gp ? p0 : q0, po_ = gp ? p1 : q1;
        const f16x2 xif = gp ? xqh : xvh;
        const f16x2 xgo = gp ? xvh : xqh;
        const float gi = sigm (pi_ + (float)xif.x);
        const float gf = sigm (pf_ + (float)xif.y);
        const float gg = tanhr(pg_ + (float)xgo.x);
        const float go = sigm (po_ + (float)xgo.y);
        cst = gf*cst + gi*gg;
        const float hvv = go * tanhr(cst);
        if ((mw >> (t & 31)) & 1) pooled += hvv;
        if (!gp) *(f16*)(smem + 131072 + ((t+1) & 1)*512 + j*2) = (f16)hvv;
        __syncthreads();
    }
    if (!gp) pool[b*H_ + j] = pooled;
}

// ---------------- head: len scan + pooled mean -> relu(lin1) -> lin2 ----------------
__global__ __launch_bounds__(256) void head_k(
    const int* __restrict__ x,
    const float* __restrict__ pool,
    const float* __restrict__ w1, const float* __restrict__ b1,
    const float* __restrict__ w2, const float* __restrict__ b2,
    float* __restrict__ out)
{
    __shared__ float pl[256];
    __shared__ float l1[512];
    __shared__ int wcnt[4];
    const int b = blockIdx.x, tid = threadIdx.x;
    const int is64 = detect64(x);
    const int* xrow = x + (((size_t)b * T_) << is64);
    int cnt = 0;
    for (int k = tid; k < T_; k += 256) cnt += (xrow[(size_t)k << is64] != 0);
    #pragma unroll
    for (int s = 32; s > 0; s >>= 1) cnt += __shfl_xor(cnt, s);
    if ((tid & 63) == 0) wcnt[tid >> 6] = cnt;
    __syncthreads();
    const float inv = 1.f / (float)(wcnt[0] + wcnt[1] + wcnt[2] + wcnt[3]);
    pl[tid] = pool[b*256 + tid] * inv;
    __syncthreads();
    for (int o = tid; o < 512; o += 256) {
        const float4* wrow = (const float4*)(w1 + (size_t)o*256);
        float s = b1[o];
        #pragma unroll 8
        for (int k = 0; k < 64; ++k) {
            float4 wv = wrow[k];
            s += pl[k*4+0]*wv.x + pl[k*4+1]*wv.y + pl[k*4+2]*wv.z + pl[k*4+3]*wv.w;
        }
        l1[o] = fmaxf(s, 0.f);
    }
    __syncthreads();
    if (tid < 20) {
        const float4* wrow = (const float4*)(w2 + (size_t)tid*512);
        float s = b2[tid];
        #pragma unroll 8
        for (int k = 0; k < 128; ++k) {
            float4 wv = wrow[k];
            s += l1[k*4+0]*wv.x + l1[k*4+1]*wv.y + l1[k*4+2]*wv.z + l1[k*4+3]*wv.w;
        }
        out[b*20 + tid] = s;
    }
}

extern "C" void kernel_launch(void* const* d_in, const int* in_sizes, int n_in,
                              void* d_out, int out_size, void* d_ws, size_t ws_size,
                              hipStream_t stream) {
    (void)in_sizes; (void)n_in; (void)out_size; (void)ws_size;
    const int*   x    = (const int*)d_in[0];
    const float* emb  = (const float*)d_in[1];
    const float* w_ih = (const float*)d_in[2];
    const float* w_hh = (const float*)d_in[3];
    const float* b_ih = (const float*)d_in[4];
    const float* b_hh = (const float*)d_in[5];
    const float* w1   = (const float*)d_in[6];
    const float* b1   = (const float*)d_in[7];
    const float* w2   = (const float*)d_in[8];
    const float* b2   = (const float*)d_in[9];
    float* out = (float*)d_out;
    char* ws = (char*)d_ws;

    f16*      xg    = (f16*)(ws + WS_XG);
    f16*      wih16 = (f16*)(ws + WS_WIH);
    unsigned* wreg  = (unsigned*)(ws + WS_WREG);
    uint4*    wlds  = (uint4*)(ws + WS_WLDS);
    unsigned* mb    = (unsigned*)(ws + WS_MB);
    float*    bsum  = (float*)(ws + WS_BSUM);
    float*    pool  = (float*)(ws + WS_POOL);

    hipLaunchKernelGGL(prep_k, dim3(512), dim3(256), 0, stream,
                       x, w_ih, w_hh, b_ih, b_hh, wih16, wreg, wlds, mb, bsum);
    hipLaunchKernelGGL(gemm_xg_k, dim3(4096), dim3(256), 0, stream,
                       x, emb, wih16, bsum, xg);
    hipLaunchKernelGGL(recur_k, dim3(32), dim3(512), LDS_BYTES, stream,
                       xg, wreg, wlds, mb, pool);
    hipLaunchKernelGGL(head_k, dim3(32), dim3(256), 0, stream,
                       x, pool, w1, b1, w2, b2, out);
}

// Round 8
// 4378.687 us; speedup vs baseline: 2.6063x; 1.0175x over previous
//
#include <hip/hip_runtime.h>
#include <hip/hip_fp16.h>

typedef _Float16 f16;
typedef _Float16 f16x2 __attribute__((ext_vector_type(2)));
typedef _Float16 f16x8 __attribute__((ext_vector_type(8)));
typedef float f32x4 __attribute__((ext_vector_type(4)));

#define B_    32
#define T_    2048
#define E_    512
#define H_    256
#define G4_   1024
#define VOCAB_ 50257

// ---------------- workspace layout (bytes) ----------------
static const size_t WS_XG   = 0;            // f16 [65536][1024] = 134217728
static const size_t WS_WIH  = 134217728ull; // f16 [1024][512]   = 1048576
static const size_t WS_WREG = 135266304ull; // uint4 [45][512]   = 368640
static const size_t WS_WLDS = 135634944ull; // uint4 [8][19][64] = 155648
static const size_t WS_MB   = 135790592ull; // u32 [32][64]      = 8192
static const size_t WS_BSUM = 135798784ull; // f32 [1024]        = 4096
static const size_t WS_POOL = 135802880ull; // f32 [32][256]     = 32768

// recur dynamic LDS: [0,155648) B-frags [wv][s19][lane]x16B; [155648,+1024) h dbuf
#define HB_OFF   155648
#define LDS_BYTES 156672

__device__ __forceinline__ unsigned pack2f(float a, float b) {
    f16x2 h; h.x = (f16)a; h.y = (f16)b;
    return __builtin_bit_cast(unsigned, h);
}

__device__ __forceinline__ float sigm(float v) {
    return 1.f / (1.f + exp2f(-1.44269504f * v));
}
__device__ __forceinline__ float tanhr(float v) {
    float t = exp2f(-2.88539008f * fabsf(v));   // e^(-2|v|)
    float r = (1.f - t) / (1.f + t);
    return v < 0.f ? -r : r;
}

__device__ __forceinline__ int detect64(const int* x) {
    return (x[1] == 0 && x[3] == 0 && x[5] == 0) ? 1 : 0;
}

// ---------------- prep ----------------
// recur MFMA geometry: wave wv owns n-tiles nt = q*16 + wv*2 + c (q=0..3,c=0..1),
// i.e. gates G = q*256 + wv*32 + c*16 + (lane&15); k-tiles kt=0..7 (32 k each).
// B-frag(nt,kt): lane holds W[G][k = kt*32 + (lane>>4)*8 .. +8] (f16x8 = uint4).
// Register frags f<45: f = kt*8+qc (kt<5), f = 40+qc (kt=5, qc<5).
// LDS frags s<19: s<3 -> kt=5,qc=5+s; s<11 -> kt=6,qc=s-3; else kt=7,qc=s-11.
__global__ void prep_k(const int* __restrict__ x,
                       const float* __restrict__ w_ih, const float* __restrict__ w_hh,
                       const float* __restrict__ b_ih, const float* __restrict__ b_hh,
                       f16* __restrict__ wih16, uint4* __restrict__ wreg,
                       uint4* __restrict__ wlds, unsigned* __restrict__ mb,
                       float* __restrict__ bsum)
{
    const int gid = blockIdx.x * blockDim.x + threadIdx.x;
    const int stride = gridDim.x * blockDim.x;
    const int is64 = detect64(x);
    for (int i = gid; i < G4_*E_; i += stride) wih16[i] = (f16)w_ih[i];
    for (int i = gid; i < G4_; i += stride) bsum[i] = b_ih[i] + b_hh[i];
    for (int n = gid; n < 45*512; n += stride) {
        const int f = n >> 9, tid = n & 511;
        const int wv = tid >> 6, lane = tid & 63, li = lane & 15, lq = lane >> 4;
        int kt, qc;
        if (f < 40) { kt = f >> 3; qc = f & 7; } else { kt = 5; qc = f - 40; }
        const int q = qc >> 1, c = qc & 1;
        const int G = q*256 + wv*32 + c*16 + li;
        const int k0 = kt*32 + lq*8;
        const float* src = w_hh + (size_t)G*H_ + k0;
        uint4 v;
        v.x = pack2f(src[0], src[1]); v.y = pack2f(src[2], src[3]);
        v.z = pack2f(src[4], src[5]); v.w = pack2f(src[6], src[7]);
        wreg[n] = v;
    }
    for (int n = gid; n < 8*19*64; n += stride) {
        const int lane = n & 63, sw = n >> 6;
        const int s = sw % 19, wv = sw / 19;
        int kt, qc;
        if (s < 3)       { kt = 5; qc = 5 + s; }
        else if (s < 11) { kt = 6; qc = s - 3; }
        else             { kt = 7; qc = s - 11; }
        const int q = qc >> 1, c = qc & 1;
        const int G = q*256 + wv*32 + c*16 + (lane & 15);
        const int k0 = kt*32 + (lane >> 4)*8;
        const float* src = w_hh + (size_t)G*H_ + k0;
        uint4 v;
        v.x = pack2f(src[0], src[1]); v.y = pack2f(src[2], src[3]);
        v.z = pack2f(src[4], src[5]); v.w = pack2f(src[6], src[7]);
        wlds[n] = v;
    }
    for (int i = gid; i < 32*64; i += stride) {
        const int b = i >> 6, wd = i & 63;
        unsigned word = 0;
        for (int tt = 0; tt < 32; ++tt) {
            const size_t ti = ((size_t)b*T_ + wd*32 + tt) << is64;
            word |= (x[ti] != 0 ? 1u : 0u) << tt;
        }
        mb[i] = word;
    }
}

// ---------------- GEMM: xg[t][j*4+gt] = (f16(emb[x]) @ f16(w_ih)^T + bsum) permuted ----------------
__global__ __launch_bounds__(256) void gemm_xg_k(
    const int* __restrict__ x, const float* __restrict__ emb,
    const f16* __restrict__ wih, const float* __restrict__ bsum,
    f16* __restrict__ xg)
{
    __shared__ f16 As[128*32];
    __shared__ f16 Bs[128*32];
    const int tid = threadIdx.x;
    const int bid = blockIdx.x;
    const int mt = bid >> 3, nt = bid & 7;
    const int wv = tid >> 6, lane = tid & 63;
    const int wm = wv & 1, wn = wv >> 1;
    const int ml = lane & 15, kg = lane >> 4;
    const int is64 = detect64(x);
    const int r = tid >> 1, kh = tid & 1;
    int tok = x[(size_t)(mt*128 + r) << is64];
    tok = tok < 0 ? 0 : (tok >= VOCAB_ ? VOCAB_ - 1 : tok);
    const float* arow = emb + (size_t)tok * E_ + kh*16;
    const f16*   brow = wih + (size_t)(nt*128 + r) * E_ + kh*16;

    f32x4 acc[4][4] = {};
    for (int kk = 0; kk < 16; ++kk) {
        const int k0 = kk * 32;
        float4 a0 = *(const float4*)(arow + k0 + 0);
        float4 a1 = *(const float4*)(arow + k0 + 4);
        float4 a2 = *(const float4*)(arow + k0 + 8);
        float4 a3 = *(const float4*)(arow + k0 + 12);
        uint4 bu0 = *(const uint4*)(brow + k0);
        uint4 bu1 = *(const uint4*)(brow + k0 + 8);
        uint4 au0, au1;
        au0.x = pack2f(a0.x, a0.y); au0.y = pack2f(a0.z, a0.w);
        au0.z = pack2f(a1.x, a1.y); au0.w = pack2f(a1.z, a1.w);
        au1.x = pack2f(a2.x, a2.y); au1.y = pack2f(a2.z, a2.w);
        au1.z = pack2f(a3.x, a3.y); au1.w = pack2f(a3.z, a3.w);
        __syncthreads();
        *(uint4*)(&As[r*32 + kh*16 + 0]) = au0;
        *(uint4*)(&As[r*32 + kh*16 + 8]) = au1;
        *(uint4*)(&Bs[r*32 + kh*16 + 0]) = bu0;
        *(uint4*)(&Bs[r*32 + kh*16 + 8]) = bu1;
        __syncthreads();
        f16x8 af[4], bf[4];
        #pragma unroll
        for (int i = 0; i < 4; ++i) {
            af[i] = *(const f16x8*)(&As[(wm*64 + i*16 + ml)*32 + kg*8]);
            bf[i] = *(const f16x8*)(&Bs[(wn*64 + i*16 + ml)*32 + kg*8]);
        }
        #pragma unroll
        for (int i = 0; i < 4; ++i)
            #pragma unroll
            for (int j = 0; j < 4; ++j)
                acc[i][j] = __builtin_amdgcn_mfma_f32_16x16x32_f16(af[i], bf[j], acc[i][j], 0, 0, 0);
    }
    #pragma unroll
    for (int j = 0; j < 4; ++j) {
        const int gc = nt*128 + wn*64 + j*16 + ml;
        const float bs = bsum[gc];
        const int pc = ((gc & 255) << 2) | (gc >> 8);   // gate-interleaved column
        #pragma unroll
        for (int i = 0; i < 4; ++i) {
            #pragma unroll
            for (int q = 0; q < 4; ++q) {
                const int gr = mt*128 + wm*64 + i*16 + kg*4 + q;
                xg[(size_t)gr*G4_ + pc] = (f16)(acc[i][j][q] + bs);
            }
        }
    }
}

// ---------------- recurrence: full MFMA; 1 block = 1 batch ----------------
// A = h broadcast to all 16 rows (LDS addr depends only on lane>>4) -> D rows
// identical -> every lane holds p[G = nt*16 + (lane&15)] in acc reg 0.
// Wave wv covers gates q*256 + wv*32 + {0..31}: all 4 gate types of j-block ->
// c/h update fully in-lane (16-fold replicated; lanes<16 write h & pool).
__global__ __attribute__((amdgpu_flat_work_group_size(512, 512), amdgpu_waves_per_eu(2, 2)))
void recur_k(const f16* __restrict__ xg,
             const uint4* __restrict__ wreg_g, const uint4* __restrict__ wlds_g,
             const unsigned* __restrict__ mb,
             float* __restrict__ pool)
{
    extern __shared__ char smem[];
    const int tid = threadIdx.x, b = blockIdx.x;
    const int wv = tid >> 6, lane = tid & 63;
    const int li = lane & 15, lq16 = (lane >> 4) * 16;
    const int j0 = wv*32 + li, j1 = j0 + 16;

    // register-resident B fragments (40 pinned + 5 floating)
    f16x8 wb[45];
    #pragma unroll
    for (int f = 0; f < 45; ++f)
        wb[f] = *(const f16x8*)(wreg_g + (size_t)f*512 + tid);
    #pragma unroll
    for (int f = 0; f < 40; ++f) asm volatile("" : "+v"(wb[f]));
    // LDS-resident B fragments
    {
        uint4* wl = (uint4*)smem;
        #pragma unroll
        for (int s = 0; s < 19; ++s)
            wl[(wv*19 + s)*64 + lane] = wlds_g[(wv*19 + s)*64 + lane];
    }
    if (tid < 256) ((unsigned*)(smem + HB_OFF))[tid] = 0u;   // zero both h buffers

    const char* xgrow = (const char*)xg + (size_t)b * T_ * 2048;
    const char* wbase = smem + wv*19*1024;
    float c0 = 0.f, c1 = 0.f, pooled0 = 0.f, pooled1 = 0.f;
    unsigned mw = 0;
    __syncthreads();

    for (int t = 0; t < T_; ++t) {
        const char* hb = smem + HB_OFF + (t & 1)*512;
        // prefetch xg (b64 per j) + mask word
        uint2 xv0 = *(const uint2*)(xgrow + (size_t)t*2048 + j0*8);
        uint2 xv1 = *(const uint2*)(xgrow + (size_t)t*2048 + j1*8);
        if ((t & 31) == 0) mw = mb[b*64 + (t >> 5)];

        f32x4 acc[8];
        #pragma unroll
        for (int i = 0; i < 8; ++i) acc[i] = (f32x4){0.f, 0.f, 0.f, 0.f};

        // kt 0..4: pure register B
        #pragma unroll
        for (int kt = 0; kt < 5; ++kt) {
            f16x8 a = *(const f16x8*)(hb + kt*64 + lq16);
            #pragma unroll
            for (int qc = 0; qc < 8; ++qc)
                acc[qc] = __builtin_amdgcn_mfma_f32_16x16x32_f16(a, wb[kt*8 + qc], acc[qc], 0, 0, 0);
        }
        // kt 5: 5 register + 3 LDS frags
        {
            f16x8 a = *(const f16x8*)(hb + 5*64 + lq16);
            #pragma unroll
            for (int qc = 0; qc < 5; ++qc)
                acc[qc] = __builtin_amdgcn_mfma_f32_16x16x32_f16(a, wb[40 + qc], acc[qc], 0, 0, 0);
            #pragma unroll
            for (int s = 0; s < 3; ++s) {
                f16x8 wl = *(const f16x8*)(wbase + s*1024 + lane*16);
                acc[5 + s] = __builtin_amdgcn_mfma_f32_16x16x32_f16(a, wl, acc[5 + s], 0, 0, 0);
            }
        }
        // kt 6: LDS frags s=3..10
        {
            f16x8 a = *(const f16x8*)(hb + 6*64 + lq16);
            #pragma unroll
            for (int qc = 0; qc < 8; ++qc) {
                f16x8 wl = *(const f16x8*)(wbase + (3 + qc)*1024 + lane*16);
                acc[qc] = __builtin_amdgcn_mfma_f32_16x16x32_f16(a, wl, acc[qc], 0, 0, 0);
            }
        }
        // kt 7: LDS frags s=11..18
        {
            f16x8 a = *(const f16x8*)(hb + 7*64 + lq16);
            #pragma unroll
            for (int qc = 0; qc < 8; ++qc) {
                f16x8 wl = *(const f16x8*)(wbase + (11 + qc)*1024 + lane*16);
                acc[qc] = __builtin_amdgcn_mfma_f32_16x16x32_f16(a, wl, acc[qc], 0, 0, 0);
            }
        }

        // gate tail, fully in-lane (acc[q*2+c][0] = p for gate q of j_c)
        const f16x2 xa0 = __builtin_bit_cast(f16x2, xv0.x);
        const f16x2 xb0 = __builtin_bit_cast(f16x2, xv0.y);
        const f16x2 xa1 = __builtin_bit_cast(f16x2, xv1.x);
        const f16x2 xb1 = __builtin_bit_cast(f16x2, xv1.y);
        const float gi0 = sigm (acc[0][0] + (float)xa0.x);
        const float gf0 = sigm (acc[2][0] + (float)xa0.y);
        const float gg0 = tanhr(acc[4][0] + (float)xb0.x);
        const float go0 = sigm (acc[6][0] + (float)xb0.y);
        const float gi1 = sigm (acc[1][0] + (float)xa1.x);
        const float gf1 = sigm (acc[3][0] + (float)xa1.y);
        const float gg1 = tanhr(acc[5][0] + (float)xb1.x);
        const float go1 = sigm (acc[7][0] + (float)xb1.y);
        c0 = gf0*c0 + gi0*gg0;
        c1 = gf1*c1 + gi1*gg1;
        const float h0 = go0 * tanhr(c0);
        const float h1 = go1 * tanhr(c1);
        const float madd = ((mw >> (t & 31)) & 1) ? 1.f : 0.f;
        pooled0 += madd * h0;
        pooled1 += madd * h1;
        char* hn = smem + HB_OFF + ((t + 1) & 1)*512;
        if (lane < 16) {
            *(f16*)(hn + j0*2) = (f16)h0;
            *(f16*)(hn + j1*2) = (f16)h1;
        }
        __syncthreads();
    }
    if (lane < 16) {
        pool[b*H_ + j0] = pooled0;
        pool[b*H_ + j1] = pooled1;
    }
}

// ---------------- head: len scan + pooled mean -> relu(lin1) -> lin2 ----------------
__global__ __launch_bounds__(256) void head_k(
    const int* __restrict__ x,
    const float* __restrict__ pool,
    const float* __restrict__ w1, const float* __restrict__ b1,
    const float* __restrict__ w2, const float* __restrict__ b2,
    float* __restrict__ out)
{
    __shared__ float pl[256];
    __shared__ float l1[512];
    __shared__ int wcnt[4];
    const int b = blockIdx.x, tid = threadIdx.x;
    const int is64 = detect64(x);
    const int* xrow = x + (((size_t)b * T_) << is64);
    int cnt = 0;
    for (int k = tid; k < T_; k += 256) cnt += (xrow[(size_t)k << is64] != 0);
    #pragma unroll
    for (int s = 32; s > 0; s >>= 1) cnt += __shfl_xor(cnt, s);
    if ((tid & 63) == 0) wcnt[tid >> 6] = cnt;
    __syncthreads();
    const float inv = 1.f / (float)(wcnt[0] + wcnt[1] + wcnt[2] + wcnt[3]);
    pl[tid] = pool[b*256 + tid] * inv;
    __syncthreads();
    for (int o = tid; o < 512; o += 256) {
        const float4* wrow = (const float4*)(w1 + (size_t)o*256);
        float s = b1[o];
        #pragma unroll 8
        for (int k = 0; k < 64; ++k) {
            float4 wv = wrow[k];
            s += pl[k*4+0]*wv.x + pl[k*4+1]*wv.y + pl[k*4+2]*wv.z + pl[k*4+3]*wv.w;
        }
        l1[o] = fmaxf(s, 0.f);
    }
    __syncthreads();
    if (tid < 20) {
        const float4* wrow = (const float4*)(w2 + (size_t)tid*512);
        float s = b2[tid];
        #pragma unroll 8
        for (int k = 0; k < 128; ++k) {
            float4 wv = wrow[k];
            s += l1[k*4+0]*wv.x + l1[k*4+1]*wv.y + l1[k*4+2]*wv.z + l1[k*4+3]*wv.w;
        }
        out[b*20 + tid] = s;
    }
}

extern "C" void kernel_launch(void* const* d_in, const int* in_sizes, int n_in,
                              void* d_out, int out_size, void* d_ws, size_t ws_size,
                              hipStream_t stream) {
    (void)in_sizes; (void)n_in; (void)out_size; (void)ws_size;
    const int*   x    = (const int*)d_in[0];
    const float* emb  = (const float*)d_in[1];
    const float* w_ih = (const float*)d_in[2];
    const float* w_hh = (const float*)d_in[3];
    const float* b_ih = (const float*)d_in[4];
    const float* b_hh = (const float*)d_in[5];
    const float* w1   = (const float*)d_in[6];
    const float* b1   = (const float*)d_in[7];
    const float* w2   = (const float*)d_in[8];
    const float* b2   = (const float*)d_in[9];
    float* out = (float*)d_out;
    char* ws = (char*)d_ws;

    f16*      xg    = (f16*)(ws + WS_XG);
    f16*      wih16 = (f16*)(ws + WS_WIH);
    uint4*    wreg  = (uint4*)(ws + WS_WREG);
    uint4*    wlds  = (uint4*)(ws + WS_WLDS);
    unsigned* mb    = (unsigned*)(ws + WS_MB);
    float*    bsum  = (float*)(ws + WS_BSUM);
    float*    pool  = (float*)(ws + WS_POOL);

    hipLaunchKernelGGL(prep_k, dim3(512), dim3(256), 0, stream,
                       x, w_ih, w_hh, b_ih, b_hh, wih16, wreg, wlds, mb, bsum);
    hipLaunchKernelGGL(gemm_xg_k, dim3(4096), dim3(256), 0, stream,
                       x, emb, wih16, bsum, xg);
    hipLaunchKernelGGL(recur_k, dim3(32), dim3(512), LDS_BYTES, stream,
                       xg, wreg, wlds, mb, pool);
    hipLaunchKernelGGL(head_k, dim3(32), dim3(256), 0, stream,
                       x, pool, w1, b1, w2, b2, out);
}